// Round 1
// 393.091 us; speedup vs baseline: 1.0038x; 1.0038x over previous
//
#include <hip/hip_runtime.h>

#define NN 65536
#define NE 1048576
#define HID 80

typedef unsigned int u32;
typedef unsigned short u16;
typedef unsigned long long u64;

__device__ __forceinline__ u16 f2bf(float f) {
  u32 u = __float_as_uint(f);
  u = (u + 0x7fffu + ((u >> 16) & 1u)) >> 16;  // RNE
  return (u16)u;
}
__device__ __forceinline__ float bfhi(u32 packed) {
  return __uint_as_float(packed & 0xffff0000u);
}
__device__ __forceinline__ float bflo(u32 packed) {
  return __uint_as_float(packed << 16);
}

// ---------------- input projection: h = x @ W_in + b_in ----------------
// hmain[n][64] = logical comps 0..63; htail[n][16] = comps 64..79 (L2-res.)
__global__ __launch_bounds__(256) void k_in(const float* __restrict__ x,
    const float* __restrict__ W, const float* __restrict__ b,
    u16* __restrict__ hmain, u16* __restrict__ htail) {
  int idx = blockIdx.x * 256 + threadIdx.x;
  if (idx >= NN * HID) return;
  int n = idx / HID, l = idx % HID;
  const float* xr = x + n * 16;
  float acc = b[l];
#pragma unroll
  for (int k = 0; k < 16; k++) acc += xr[k] * W[k * HID + l];
  u16 v = f2bf(acc);
  if (l < 64) hmain[(size_t)n * 64 + l] = v;
  else htail[(size_t)n * 16 + (l - 64)] = v;
}

// ---------------- CSR build ----------------
// hist + per-edge rank, batched x8. Block 0 also zeroes dcnt (folds a
// memset launch; k_nb_scan's atomics on dcnt only run after this kernel).
__global__ __launch_bounds__(256) void k_hist(const int* __restrict__ dst,
    int* __restrict__ counts, int* __restrict__ rank, int* __restrict__ dcnt) {
  if (blockIdx.x == 0 && threadIdx.x < 16) dcnt[threadIdx.x] = 0;
  int base = blockIdx.x * 2048 + threadIdx.x;
#pragma unroll
  for (int k = 0; k < 8; k++) {
    int idx = base + k * 256;
    rank[idx] = atomicAdd(&counts[dst[idx]], 1);
  }
}

// merged: blocks 0..63 = exclusive scan of counts padded to x8 (scan1);
// blocks 64..319 = degree-bucket classify (nbucket). Both only read counts;
// independent outputs -> one launch instead of two.
__global__ __launch_bounds__(256) void k_nb_scan(const int* __restrict__ counts,
    int* __restrict__ offsets, int* __restrict__ blocksum,
    int* __restrict__ dcnt, int* __restrict__ brank, int* __restrict__ bidx) {
  __shared__ int sc[256];
  int t = threadIdx.x;
  if (blockIdx.x < 64) {
    int base = blockIdx.x * 1024 + t * 4;
    int p0 = (counts[base] + 7) & ~7;
    int p1 = (counts[base + 1] + 7) & ~7;
    int p2 = (counts[base + 2] + 7) & ~7;
    int p3 = (counts[base + 3] + 7) & ~7;
    int s = p0 + p1 + p2 + p3;
    sc[t] = s;
    __syncthreads();
    for (int d = 1; d < 256; d <<= 1) {
      int v = (t >= d) ? sc[t - d] : 0;
      __syncthreads();
      sc[t] += v;
      __syncthreads();
    }
    int excl = sc[t] - s;
    offsets[base] = excl;
    offsets[base + 1] = excl + p0;
    offsets[base + 2] = excl + p0 + p1;
    offsets[base + 3] = excl + p0 + p1 + p2;
    if (t == 255) blocksum[blockIdx.x] = sc[255];
  } else {
    // reversed buckets: heaviest-degree nodes dispatch first (straggler fix)
    int n = (blockIdx.x - 64) * 256 + t;
    int degp = (counts[n] + 7) & ~7;
    int b = 15 - min(degp >> 3, 15);
    int lane = t & 63;
    int base = 0;
#pragma unroll 1
    for (int bb = 0; bb < 16; bb++) {
      u64 m = __ballot(b == bb);
      if (b == bb) {
        int leader = __ffsll((long long)m) - 1;
        int lr = __popcll(m & ((lane == 63) ? ~0ull >> 1 : ((1ull << lane) - 1)));
        int bs = 0;
        if (lane == leader) bs = atomicAdd(&dcnt[bb], __popcll(m));
        bs = __shfl(bs, leader, 64);
        base = bs + lr;
      }
    }
    brank[n] = base;
    bidx[n] = b;
  }
}

// block 0: scan blocksum[64]; block 1: scan dcnt[16]  (merged, saves a launch)
__global__ __launch_bounds__(64) void k_scan2(int* __restrict__ blocksum,
                                              int* __restrict__ dcnt) {
  int t = threadIdx.x;
  if (blockIdx.x == 0) {
    int v = blocksum[t];
    int incl = v;
#pragma unroll
    for (int d = 1; d < 64; d <<= 1) {
      int o = __shfl_up(incl, d, 64);
      if (t >= d) incl += o;
    }
    blocksum[t] = incl - v;
  } else {
    if (t >= 16) return;
    int v = dcnt[t];
    int incl = v;
#pragma unroll
    for (int d = 1; d < 16; d <<= 1) {
      int o = __shfl_up(incl, d, 64);
      if (t >= d) incl += o;
    }
    dcnt[t] = incl - v;
  }
}

// merged per-node finalize: offsets += blocksum (scan3) + zero pad slots
// + write nperm. Edge records are SoA now: esrc (u16 src) + eat (8B attrs).
__global__ __launch_bounds__(256) void k_node_fin(int* __restrict__ offsets,
    const int* __restrict__ blocksum, const int* __restrict__ counts,
    u16* __restrict__ esrc, uint2* __restrict__ eat,
    const int* __restrict__ dcnt, const int* __restrict__ brank,
    const int* __restrict__ bidx, int* __restrict__ nperm) {
  int n = blockIdx.x * 256 + threadIdx.x;
  int off = offsets[n] + blocksum[n >> 10];
  offsets[n] = off;
  int deg = counts[n];
  int degp = (deg + 7) & ~7;
  uint2 z2 = make_uint2(0u, 0u);
  for (int e = deg; e < degp; e++) {
    esrc[off + e] = 0;       // gathers node 0 harmlessly, factors are 0
    eat[off + e] = z2;
  }
  nperm[dcnt[bidx[n]] + brank[n]] = n;
}

// pure scatter, no atomic: pos = offsets[dst] + rank   (batched x8)
// 10B/edge instead of 16B: u16 src + uint2 bf16 attrs.
__global__ __launch_bounds__(256) void k_fill(const int* __restrict__ src,
    const int* __restrict__ dst, const float4* __restrict__ eattr,
    const int* __restrict__ offsets, const int* __restrict__ rank,
    u16* __restrict__ esrc, uint2* __restrict__ eat) {
  int base = blockIdx.x * 2048 + threadIdx.x;
#pragma unroll
  for (int k = 0; k < 8; k++) {
    int idx = base + k * 256;
    int d = dst[idx];
    float4 ea = eattr[idx];
    int s = src[idx];
    u32 c01 = (u32)f2bf(ea.x) | ((u32)f2bf(ea.y) << 16);
    u32 c23 = (u32)f2bf(ea.z) | ((u32)f2bf(ea.w) << 16);
    int pos = offsets[d] + rank[idx];
    esrc[pos] = (u16)s;
    eat[pos] = make_uint2(c01, c23);
  }
}

// ---------------- per-layer message + aggregate + post-matmul ----------------
// Round-14 proven optimum structure: 8 nodes/block, quarter-wave per node,
// manual 2-batch statically-indexed pipeline, (128,3) cap -> no spill.
// This round: edge stream shrunk 16B->10B (u16 src + 8B attr SoA); LAST
// template fuses relu + @W_out + b_out into layer 3 (kills k_out pass and
// the layer-3 h write).
template <int LAST>
__global__ __launch_bounds__(128, 3) void k_msg(const u16* __restrict__ hmain,
    const u16* __restrict__ htail, u16* __restrict__ omain,
    u16* __restrict__ otail,
    const float* __restrict__ w1, const float* __restrict__ w2,
    const float* __restrict__ w3, const float* __restrict__ w4,
    const int* __restrict__ offsets, const int* __restrict__ counts,
    const int* __restrict__ nperm, const u16* __restrict__ esrc,
    const uint2* __restrict__ eat, const float* __restrict__ Wout,
    const float* __restrict__ bout, float* __restrict__ outp) {
  __shared__ float Rlds[8][4][81];
  int tid = threadIdx.x;
  const int q = tid >> 4;
  const int c = tid & 15;
  const int n = nperm[blockIdx.x * 8 + q];

  float R[4][5];
#pragma unroll
  for (int j = 0; j < 4; j++)
#pragma unroll
    for (int i = 0; i < 5; i++) R[j][i] = 0.f;

  const int start = offsets[n];
  const int degp = (counts[n] + 7) & ~7;
  const int B = degp >> 3;
  const uint2* hrow = (const uint2*)hmain + c;
  const u16* trow = htail + c;

  int i = 0;
  for (; i + 2 <= B; i += 2) {
    const int baseA = start + 8 * i;
    const int baseB = baseA + 8;
    u32 sA[8], sB[8];
    uint2 aA[8], aB[8];
#pragma unroll
    for (int k = 0; k < 8; k++) sA[k] = esrc[baseA + k];
#pragma unroll
    for (int k = 0; k < 8; k++) aA[k] = eat[baseA + k];
#pragma unroll
    for (int k = 0; k < 8; k++) sB[k] = esrc[baseB + k];
#pragma unroll
    for (int k = 0; k < 8; k++) aB[k] = eat[baseB + k];
    uint2 hA[8], hB[8];
    u32 tA[8], tB[8];
#pragma unroll
    for (int k = 0; k < 8; k++) {
      size_t s16 = (size_t)sA[k] * 16;
      hA[k] = hrow[s16];
      tA[k] = trow[s16];
    }
#pragma unroll
    for (int k = 0; k < 8; k++) {
      size_t s16 = (size_t)sB[k] * 16;
      hB[k] = hrow[s16];
      tB[k] = trow[s16];
    }
#pragma unroll
    for (int k = 0; k < 8; k++) {
      float A0 = bflo(hA[k].x), A1 = bfhi(hA[k].x);
      float A2 = bflo(hA[k].y), A3 = bfhi(hA[k].y);
      float A4 = bflo(tA[k]);
      float f0 = bflo(aA[k].x), f1 = bfhi(aA[k].x);
      float f2 = bflo(aA[k].y), f3 = bfhi(aA[k].y);
      R[0][0] += f0 * A0; R[0][1] += f0 * A1; R[0][2] += f0 * A2;
      R[0][3] += f0 * A3; R[0][4] += f0 * A4;
      R[1][0] += f1 * A0; R[1][1] += f1 * A1; R[1][2] += f1 * A2;
      R[1][3] += f1 * A3; R[1][4] += f1 * A4;
      R[2][0] += f2 * A0; R[2][1] += f2 * A1; R[2][2] += f2 * A2;
      R[2][3] += f2 * A3; R[2][4] += f2 * A4;
      R[3][0] += f3 * A0; R[3][1] += f3 * A1; R[3][2] += f3 * A2;
      R[3][3] += f3 * A3; R[3][4] += f3 * A4;
    }
#pragma unroll
    for (int k = 0; k < 8; k++) {
      float A0 = bflo(hB[k].x), A1 = bfhi(hB[k].x);
      float A2 = bflo(hB[k].y), A3 = bfhi(hB[k].y);
      float A4 = bflo(tB[k]);
      float f0 = bflo(aB[k].x), f1 = bfhi(aB[k].x);
      float f2 = bflo(aB[k].y), f3 = bfhi(aB[k].y);
      R[0][0] += f0 * A0; R[0][1] += f0 * A1; R[0][2] += f0 * A2;
      R[0][3] += f0 * A3; R[0][4] += f0 * A4;
      R[1][0] += f1 * A0; R[1][1] += f1 * A1; R[1][2] += f1 * A2;
      R[1][3] += f1 * A3; R[1][4] += f1 * A4;
      R[2][0] += f2 * A0; R[2][1] += f2 * A1; R[2][2] += f2 * A2;
      R[2][3] += f2 * A3; R[2][4] += f2 * A4;
      R[3][0] += f3 * A0; R[3][1] += f3 * A1; R[3][2] += f3 * A2;
      R[3][3] += f3 * A3; R[3][4] += f3 * A4;
    }
  }
  if (i < B) {
    const int baseA = start + 8 * i;
    u32 sA[8];
    uint2 aA[8];
#pragma unroll
    for (int k = 0; k < 8; k++) sA[k] = esrc[baseA + k];
#pragma unroll
    for (int k = 0; k < 8; k++) aA[k] = eat[baseA + k];
    uint2 hA[8];
    u32 tA[8];
#pragma unroll
    for (int k = 0; k < 8; k++) {
      size_t s16 = (size_t)sA[k] * 16;
      hA[k] = hrow[s16];
      tA[k] = trow[s16];
    }
#pragma unroll
    for (int k = 0; k < 8; k++) {
      float A0 = bflo(hA[k].x), A1 = bfhi(hA[k].x);
      float A2 = bflo(hA[k].y), A3 = bfhi(hA[k].y);
      float A4 = bflo(tA[k]);
      float f0 = bflo(aA[k].x), f1 = bfhi(aA[k].x);
      float f2 = bflo(aA[k].y), f3 = bfhi(aA[k].y);
      R[0][0] += f0 * A0; R[0][1] += f0 * A1; R[0][2] += f0 * A2;
      R[0][3] += f0 * A3; R[0][4] += f0 * A4;
      R[1][0] += f1 * A0; R[1][1] += f1 * A1; R[1][2] += f1 * A2;
      R[1][3] += f1 * A3; R[1][4] += f1 * A4;
      R[2][0] += f2 * A0; R[2][1] += f2 * A1; R[2][2] += f2 * A2;
      R[2][3] += f2 * A3; R[2][4] += f2 * A4;
      R[3][0] += f3 * A0; R[3][1] += f3 * A1; R[3][2] += f3 * A2;
      R[3][3] += f3 * A3; R[3][4] += f3 * A4;
    }
  }

  // transpose into component-indexed LDS (quarter-private slice, wave-sync)
#pragma unroll
  for (int j = 0; j < 4; j++) {
#pragma unroll
    for (int k = 0; k < 4; k++) Rlds[q][j][4 * c + k] = R[j][k];
    Rlds[q][j][64 + c] = R[j][4];
  }

  // norm constants: 1/sqrt2 * path fan-in norm * 1/sqrt(DEG)
  const float C1 = 0.03125f;      // 1/(sqrt2*sqrt32*4)
  const float C2 = 0.025515518f;  // 1/(sqrt2*sqrt48*4)
  const float C3 = 0.03125f;      // 1/(sqrt2*sqrt32*4)
  const float C4 = 0.044194174f;  // 1/(sqrt2*sqrt16*4)

  u16* opm = omain + (size_t)n * 64;

  // scalar outputs c and c+16, fused over a
  float s0 = 0.f, s1 = 0.f;
#pragma unroll
  for (int a = 0; a < 32; a++) {
    float rs = Rlds[q][0][a];
    s0 += rs * w1[a * 32 + c];
    s1 += rs * w1[a * 32 + c + 16];
  }
  float t0 = 0.f, t1 = 0.f;
#pragma unroll
  for (int a = 0; a < 16; a++) {
    float T = Rlds[q][1][32 + 3 * a] + Rlds[q][2][33 + 3 * a] +
              Rlds[q][3][34 + 3 * a];
    t0 += T * w2[a * 32 + c];
    t1 += T * w2[a * 32 + c + 16];
  }

  float y[8];
  if (LAST) {
#pragma unroll
    for (int j = 0; j < 8; j++) y[j] = 0.f;
    float vs0 = C1 * s0 + C2 * t0;  // comp c
    float vs1 = C1 * s1 + C2 * t1;  // comp c+16
    vs0 = vs0 > 0.f ? vs0 : 0.f;
    vs1 = vs1 > 0.f ? vs1 : 0.f;
#pragma unroll
    for (int j = 0; j < 8; j++)
      y[j] += vs0 * Wout[c * 8 + j] + vs1 * Wout[(c + 16) * 8 + j];
  } else {
    opm[c] = f2bf(C1 * s0 + C2 * t0);
    opm[c + 16] = f2bf(C1 * s1 + C2 * t1);
  }

  // vector outputs: logical comps c2 = 32 + 16*i + c.
#pragma unroll
  for (int v2 = 0; v2 < 3; v2++) {
    int c2 = 32 + 16 * v2 + c;
    int cv = (c2 - 32) / 3, k = (c2 - 32) % 3;
    float a3 = 0.f, a4 = 0.f;
#pragma unroll
    for (int a = 0; a < 32; a++) a3 += Rlds[q][k + 1][a] * w3[a * 16 + cv];
#pragma unroll
    for (int a = 0; a < 16; a++)
      a4 += Rlds[q][0][32 + 3 * a + k] * w4[a * 16 + cv];
    float val = C3 * a3 + C4 * a4;
    if (LAST) {
      val = val > 0.f ? val : 0.f;
#pragma unroll
      for (int j = 0; j < 8; j++) y[j] += val * Wout[c2 * 8 + j];
    } else {
      u16 v = f2bf(val);
      if (v2 < 2) opm[32 + 16 * v2 + c] = v;
      else otail[(size_t)n * 16 + c] = v;
    }
  }

  if (LAST) {
    // quarter-wave (16-lane) reduction; xor masks 1,2,4,8 stay in-quarter
#pragma unroll
    for (int m = 1; m <= 8; m <<= 1) {
#pragma unroll
      for (int j = 0; j < 8; j++) y[j] += __shfl_xor(y[j], m, 64);
    }
    float w = y[0];
#pragma unroll
    for (int j = 1; j < 8; j++)
      if (c == j) w = y[j];
    if (c < 8) outp[(size_t)n * 8 + c] = w + bout[c];
  }
}

extern "C" void kernel_launch(void* const* d_in, const int* in_sizes, int n_in,
                              void* d_out, int out_size, void* d_ws,
                              size_t ws_size, hipStream_t stream) {
  const float* x = (const float*)d_in[0];
  const int* ei = (const int*)d_in[1];
  const float* eattr = (const float*)d_in[2];
  const float* W_in = (const float*)d_in[3];
  const float* b_in = (const float*)d_in[4];
  const float* tp_w1 = (const float*)d_in[5];
  const float* tp_w2 = (const float*)d_in[6];
  const float* tp_w3 = (const float*)d_in[7];
  const float* tp_w4 = (const float*)d_in[8];
  const float* W_out = (const float*)d_in[9];
  const float* b_out = (const float*)d_in[10];
  float* out = (float*)d_out;

  char* ws = (char*)d_ws;
  size_t off = 0;
  auto alloc = [&](size_t bytes) {
    void* p = ws + off;
    off += (bytes + 255) & ~size_t(255);
    return p;
  };
  const size_t NEP = (size_t)NE + 8 * (size_t)NN;
  u16* hm_a = (u16*)alloc((size_t)NN * 64 * 2);
  u16* ht_a = (u16*)alloc((size_t)NN * 16 * 2);
  u16* hm_b = (u16*)alloc((size_t)NN * 64 * 2);
  u16* ht_b = (u16*)alloc((size_t)NN * 16 * 2);
  int* counts = (int*)alloc((size_t)NN * 4);
  int* offsets = (int*)alloc((size_t)NN * 4);
  int* blocksum = (int*)alloc(64 * 4);
  int* rank = (int*)alloc((size_t)NE * 4);
  int* dcnt = (int*)alloc(16 * 4);
  int* brank = (int*)alloc((size_t)NN * 4);
  int* bidx = (int*)alloc((size_t)NN * 4);
  int* nperm = (int*)alloc((size_t)NN * 4);
  u16* esrc = (u16*)alloc(NEP * 2);
  uint2* eat = (uint2*)alloc(NEP * 8);

  const int* src = ei;
  const int* dst = ei + NE;

  hipMemsetAsync(counts, 0, (size_t)NN * 4, stream);
  k_in<<<(NN * HID + 255) / 256, 256, 0, stream>>>(x, W_in, b_in, hm_a, ht_a);
  k_hist<<<NE / 2048, 256, 0, stream>>>(dst, counts, rank, dcnt);
  k_nb_scan<<<64 + NN / 256, 256, 0, stream>>>(counts, offsets, blocksum, dcnt,
                                               brank, bidx);
  k_scan2<<<2, 64, 0, stream>>>(blocksum, dcnt);
  k_node_fin<<<NN / 256, 256, 0, stream>>>(offsets, blocksum, counts, esrc,
                                           eat, dcnt, brank, bidx, nperm);
  k_fill<<<NE / 2048, 256, 0, stream>>>(src, dst, (const float4*)eattr,
                                        offsets, rank, esrc, eat);

  u16* hmi = hm_a;
  u16* hti = ht_a;
  u16* hmo = hm_b;
  u16* hto = ht_b;
  for (int l = 0; l < 2; l++) {
    k_msg<0><<<NN / 8, 128, 0, stream>>>(hmi, hti, hmo, hto, tp_w1 + l * 1024,
                                         tp_w2 + l * 512, tp_w3 + l * 512,
                                         tp_w4 + l * 256, offsets, counts,
                                         nperm, esrc, eat, W_out, b_out, out);
    u16* t;
    t = hmi; hmi = hmo; hmo = t;
    t = hti; hti = hto; hto = t;
  }
  k_msg<1><<<NN / 8, 128, 0, stream>>>(hmi, hti, hmo, hto, tp_w1 + 2048,
                                       tp_w2 + 1024, tp_w3 + 1024, tp_w4 + 512,
                                       offsets, counts, nperm, esrc, eat,
                                       W_out, b_out, out);
}

// Round 2
// 386.111 us; speedup vs baseline: 1.0220x; 1.0181x over previous
//
#include <hip/hip_runtime.h>

#define NN 65536
#define NE 1048576
#define HID 80

typedef unsigned int u32;
typedef unsigned short u16;
typedef unsigned long long u64;

__device__ __forceinline__ u16 f2bf(float f) {
  u32 u = __float_as_uint(f);
  u = (u + 0x7fffu + ((u >> 16) & 1u)) >> 16;  // RNE
  return (u16)u;
}
__device__ __forceinline__ float bfhi(u32 packed) {
  return __uint_as_float(packed & 0xffff0000u);
}
__device__ __forceinline__ float bflo(u32 packed) {
  return __uint_as_float(packed << 16);
}

// ---------------- input projection: h = x @ W_in + b_in ----------------
// one thread per 8 output comps: float4 x-loads, uint4 bf16 store.
// hmain[n][64] = logical comps 0..63; htail[n][16] = comps 64..79 (L2-res.)
__global__ __launch_bounds__(256) void k_in(const float* __restrict__ x,
    const float* __restrict__ W, const float* __restrict__ b,
    u16* __restrict__ hmain, u16* __restrict__ htail) {
  int idx = blockIdx.x * 256 + threadIdx.x;
  if (idx >= NN * 10) return;
  int n = idx / 10, part = idx % 10;
  const float4* xr = (const float4*)(x + (size_t)n * 16);
  float4 x0 = xr[0], x1 = xr[1], x2 = xr[2], x3 = xr[3];
  const float xs[16] = {x0.x, x0.y, x0.z, x0.w, x1.x, x1.y, x1.z, x1.w,
                        x2.x, x2.y, x2.z, x2.w, x3.x, x3.y, x3.z, x3.w};
  float acc[8];
#pragma unroll
  for (int j = 0; j < 8; j++) acc[j] = b[part * 8 + j];
#pragma unroll
  for (int k = 0; k < 16; k++) {
#pragma unroll
    for (int j = 0; j < 8; j++) acc[j] += xs[k] * W[k * HID + part * 8 + j];
  }
  u32 p0 = (u32)f2bf(acc[0]) | ((u32)f2bf(acc[1]) << 16);
  u32 p1 = (u32)f2bf(acc[2]) | ((u32)f2bf(acc[3]) << 16);
  u32 p2 = (u32)f2bf(acc[4]) | ((u32)f2bf(acc[5]) << 16);
  u32 p3 = (u32)f2bf(acc[6]) | ((u32)f2bf(acc[7]) << 16);
  uint4 vv = make_uint4(p0, p1, p2, p3);
  if (part < 8)
    *(uint4*)(hmain + (size_t)n * 64 + part * 8) = vv;
  else
    *(uint4*)(htail + (size_t)n * 16 + (part - 8) * 8) = vv;
}

// ---------------- CSR build ----------------
// hist + per-edge rank, batched x8. Block 0 also zeroes dcnt (folds a
// memset launch; k_nb_scan's atomics on dcnt only run after this kernel).
__global__ __launch_bounds__(256) void k_hist(const int* __restrict__ dst,
    int* __restrict__ counts, int* __restrict__ rank, int* __restrict__ dcnt) {
  if (blockIdx.x == 0 && threadIdx.x < 16) dcnt[threadIdx.x] = 0;
  int base = blockIdx.x * 2048 + threadIdx.x;
#pragma unroll
  for (int k = 0; k < 8; k++) {
    int idx = base + k * 256;
    rank[idx] = atomicAdd(&counts[dst[idx]], 1);
  }
}

// merged: blocks 0..63 = exclusive scan of counts padded to x8 (scan1);
// blocks 64..319 = degree-bucket classify (nbucket). Both only read counts;
// independent outputs -> one launch instead of two.
__global__ __launch_bounds__(256) void k_nb_scan(const int* __restrict__ counts,
    int* __restrict__ offsets, int* __restrict__ blocksum,
    int* __restrict__ dcnt, int* __restrict__ brank, int* __restrict__ bidx) {
  __shared__ int sc[256];
  int t = threadIdx.x;
  if (blockIdx.x < 64) {
    int base = blockIdx.x * 1024 + t * 4;
    int p0 = (counts[base] + 7) & ~7;
    int p1 = (counts[base + 1] + 7) & ~7;
    int p2 = (counts[base + 2] + 7) & ~7;
    int p3 = (counts[base + 3] + 7) & ~7;
    int s = p0 + p1 + p2 + p3;
    sc[t] = s;
    __syncthreads();
    for (int d = 1; d < 256; d <<= 1) {
      int v = (t >= d) ? sc[t - d] : 0;
      __syncthreads();
      sc[t] += v;
      __syncthreads();
    }
    int excl = sc[t] - s;
    offsets[base] = excl;
    offsets[base + 1] = excl + p0;
    offsets[base + 2] = excl + p0 + p1;
    offsets[base + 3] = excl + p0 + p1 + p2;
    if (t == 255) blocksum[blockIdx.x] = sc[255];
  } else {
    // reversed buckets: heaviest-degree nodes dispatch first (straggler fix)
    int n = (blockIdx.x - 64) * 256 + t;
    int degp = (counts[n] + 7) & ~7;
    int b = 15 - min(degp >> 3, 15);
    int lane = t & 63;
    int base = 0;
#pragma unroll 1
    for (int bb = 0; bb < 16; bb++) {
      u64 m = __ballot(b == bb);
      if (b == bb) {
        int leader = __ffsll((long long)m) - 1;
        int lr = __popcll(m & ((lane == 63) ? ~0ull >> 1 : ((1ull << lane) - 1)));
        int bs = 0;
        if (lane == leader) bs = atomicAdd(&dcnt[bb], __popcll(m));
        bs = __shfl(bs, leader, 64);
        base = bs + lr;
      }
    }
    brank[n] = base;
    bidx[n] = b;
  }
}

// block 0: scan blocksum[64]; block 1: scan dcnt[16]  (merged, saves a launch)
__global__ __launch_bounds__(64) void k_scan2(int* __restrict__ blocksum,
                                              int* __restrict__ dcnt) {
  int t = threadIdx.x;
  if (blockIdx.x == 0) {
    int v = blocksum[t];
    int incl = v;
#pragma unroll
    for (int d = 1; d < 64; d <<= 1) {
      int o = __shfl_up(incl, d, 64);
      if (t >= d) incl += o;
    }
    blocksum[t] = incl - v;
  } else {
    if (t >= 16) return;
    int v = dcnt[t];
    int incl = v;
#pragma unroll
    for (int d = 1; d < 16; d <<= 1) {
      int o = __shfl_up(incl, d, 64);
      if (t >= d) incl += o;
    }
    dcnt[t] = incl - v;
  }
}

// merged per-node finalize: offsets += blocksum (scan3) + zero pad slots
// + write nperm. Edge records are SoA: esrc (u16 src) + eat (8B attrs).
__global__ __launch_bounds__(256) void k_node_fin(int* __restrict__ offsets,
    const int* __restrict__ blocksum, const int* __restrict__ counts,
    u16* __restrict__ esrc, uint2* __restrict__ eat,
    const int* __restrict__ dcnt, const int* __restrict__ brank,
    const int* __restrict__ bidx, int* __restrict__ nperm) {
  int n = blockIdx.x * 256 + threadIdx.x;
  int off = offsets[n] + blocksum[n >> 10];
  offsets[n] = off;
  int deg = counts[n];
  int degp = (deg + 7) & ~7;
  uint2 z2 = make_uint2(0u, 0u);
  for (int e = deg; e < degp; e++) {
    esrc[off + e] = 0;  // gathers node 0 harmlessly, factors are 0
    eat[off + e] = z2;
  }
  nperm[dcnt[bidx[n]] + brank[n]] = n;
}

// pure scatter, no atomic: pos = offsets[dst] + rank   (batched x8)
// 10B/edge: u16 src + uint2 bf16 attrs.
__global__ __launch_bounds__(256) void k_fill(const int* __restrict__ src,
    const int* __restrict__ dst, const float4* __restrict__ eattr,
    const int* __restrict__ offsets, const int* __restrict__ rank,
    u16* __restrict__ esrc, uint2* __restrict__ eat) {
  int base = blockIdx.x * 2048 + threadIdx.x;
#pragma unroll
  for (int k = 0; k < 8; k++) {
    int idx = base + k * 256;
    int d = dst[idx];
    float4 ea = eattr[idx];
    int s = src[idx];
    u32 c01 = (u32)f2bf(ea.x) | ((u32)f2bf(ea.y) << 16);
    u32 c23 = (u32)f2bf(ea.z) | ((u32)f2bf(ea.w) << 16);
    int pos = offsets[d] + rank[idx];
    esrc[pos] = (u16)s;
    eat[pos] = make_uint2(c01, c23);
  }
}

// ---------------- per-layer message + aggregate + post-matmul ----------------
// 8 nodes/block, quarter-wave per node, manual 2-batch statically-indexed
// pipeline, (128,3) cap -> no spill. Edge stream 10B/edge, loaded as
// PACKED lane-uniform vectors: per 8-edge batch, 1x uint4 (8 u16 srcs) +
// 4x uint4 (8 uint2 attrs) = 5 VMEM ops (r1's 16 scalar loads regressed;
// issue-bound, not bytes-bound). LAST fuses relu + @W_out + b_out.
template <int LAST>
__global__ __launch_bounds__(128, 3) void k_msg(const u16* __restrict__ hmain,
    const u16* __restrict__ htail, u16* __restrict__ omain,
    u16* __restrict__ otail,
    const float* __restrict__ w1, const float* __restrict__ w2,
    const float* __restrict__ w3, const float* __restrict__ w4,
    const int* __restrict__ offsets, const int* __restrict__ counts,
    const int* __restrict__ nperm, const u16* __restrict__ esrc,
    const uint2* __restrict__ eat, const float* __restrict__ Wout,
    const float* __restrict__ bout, float* __restrict__ outp) {
  __shared__ float Rlds[8][4][81];
  int tid = threadIdx.x;
  const int q = tid >> 4;
  const int c = tid & 15;
  const int n = nperm[blockIdx.x * 8 + q];

  float R[4][5];
#pragma unroll
  for (int j = 0; j < 4; j++)
#pragma unroll
    for (int i = 0; i < 5; i++) R[j][i] = 0.f;

  const int start = offsets[n];
  const int degp = (counts[n] + 7) & ~7;
  const int B = degp >> 3;
  const uint2* hrow = (const uint2*)hmain + c;
  const u16* trow = htail + c;

  int i = 0;
  for (; i + 2 <= B; i += 2) {
    const int baseA = start + 8 * i;
    const int baseB = baseA + 8;
    // packed lane-uniform edge loads: 5 VMEM per 8-edge batch
    uint4 spA = *(const uint4*)(esrc + baseA);
    uint4 qA0 = ((const uint4*)(eat + baseA))[0];
    uint4 qA1 = ((const uint4*)(eat + baseA))[1];
    uint4 qA2 = ((const uint4*)(eat + baseA))[2];
    uint4 qA3 = ((const uint4*)(eat + baseA))[3];
    uint4 spB = *(const uint4*)(esrc + baseB);
    uint4 qB0 = ((const uint4*)(eat + baseB))[0];
    uint4 qB1 = ((const uint4*)(eat + baseB))[1];
    uint4 qB2 = ((const uint4*)(eat + baseB))[2];
    uint4 qB3 = ((const uint4*)(eat + baseB))[3];
    u32 sA[8], sB[8];
    sA[0] = spA.x & 0xffffu; sA[1] = spA.x >> 16;
    sA[2] = spA.y & 0xffffu; sA[3] = spA.y >> 16;
    sA[4] = spA.z & 0xffffu; sA[5] = spA.z >> 16;
    sA[6] = spA.w & 0xffffu; sA[7] = spA.w >> 16;
    sB[0] = spB.x & 0xffffu; sB[1] = spB.x >> 16;
    sB[2] = spB.y & 0xffffu; sB[3] = spB.y >> 16;
    sB[4] = spB.z & 0xffffu; sB[5] = spB.z >> 16;
    sB[6] = spB.w & 0xffffu; sB[7] = spB.w >> 16;
    uint2 aA[8], aB[8];
    aA[0] = make_uint2(qA0.x, qA0.y); aA[1] = make_uint2(qA0.z, qA0.w);
    aA[2] = make_uint2(qA1.x, qA1.y); aA[3] = make_uint2(qA1.z, qA1.w);
    aA[4] = make_uint2(qA2.x, qA2.y); aA[5] = make_uint2(qA2.z, qA2.w);
    aA[6] = make_uint2(qA3.x, qA3.y); aA[7] = make_uint2(qA3.z, qA3.w);
    aB[0] = make_uint2(qB0.x, qB0.y); aB[1] = make_uint2(qB0.z, qB0.w);
    aB[2] = make_uint2(qB1.x, qB1.y); aB[3] = make_uint2(qB1.z, qB1.w);
    aB[4] = make_uint2(qB2.x, qB2.y); aB[5] = make_uint2(qB2.z, qB2.w);
    aB[6] = make_uint2(qB3.x, qB3.y); aB[7] = make_uint2(qB3.z, qB3.w);
    uint2 hA[8], hB[8];
    u32 tA[8], tB[8];
#pragma unroll
    for (int k = 0; k < 8; k++) {
      size_t s16 = (size_t)sA[k] * 16;
      hA[k] = hrow[s16];
      tA[k] = trow[s16];
    }
#pragma unroll
    for (int k = 0; k < 8; k++) {
      size_t s16 = (size_t)sB[k] * 16;
      hB[k] = hrow[s16];
      tB[k] = trow[s16];
    }
#pragma unroll
    for (int k = 0; k < 8; k++) {
      float A0 = bflo(hA[k].x), A1 = bfhi(hA[k].x);
      float A2 = bflo(hA[k].y), A3 = bfhi(hA[k].y);
      float A4 = bflo(tA[k]);
      float f0 = bflo(aA[k].x), f1 = bfhi(aA[k].x);
      float f2 = bflo(aA[k].y), f3 = bfhi(aA[k].y);
      R[0][0] += f0 * A0; R[0][1] += f0 * A1; R[0][2] += f0 * A2;
      R[0][3] += f0 * A3; R[0][4] += f0 * A4;
      R[1][0] += f1 * A0; R[1][1] += f1 * A1; R[1][2] += f1 * A2;
      R[1][3] += f1 * A3; R[1][4] += f1 * A4;
      R[2][0] += f2 * A0; R[2][1] += f2 * A1; R[2][2] += f2 * A2;
      R[2][3] += f2 * A3; R[2][4] += f2 * A4;
      R[3][0] += f3 * A0; R[3][1] += f3 * A1; R[3][2] += f3 * A2;
      R[3][3] += f3 * A3; R[3][4] += f3 * A4;
    }
#pragma unroll
    for (int k = 0; k < 8; k++) {
      float A0 = bflo(hB[k].x), A1 = bfhi(hB[k].x);
      float A2 = bflo(hB[k].y), A3 = bfhi(hB[k].y);
      float A4 = bflo(tB[k]);
      float f0 = bflo(aB[k].x), f1 = bfhi(aB[k].x);
      float f2 = bflo(aB[k].y), f3 = bfhi(aB[k].y);
      R[0][0] += f0 * A0; R[0][1] += f0 * A1; R[0][2] += f0 * A2;
      R[0][3] += f0 * A3; R[0][4] += f0 * A4;
      R[1][0] += f1 * A0; R[1][1] += f1 * A1; R[1][2] += f1 * A2;
      R[1][3] += f1 * A3; R[1][4] += f1 * A4;
      R[2][0] += f2 * A0; R[2][1] += f2 * A1; R[2][2] += f2 * A2;
      R[2][3] += f2 * A3; R[2][4] += f2 * A4;
      R[3][0] += f3 * A0; R[3][1] += f3 * A1; R[3][2] += f3 * A2;
      R[3][3] += f3 * A3; R[3][4] += f3 * A4;
    }
  }
  if (i < B) {
    const int baseA = start + 8 * i;
    uint4 spA = *(const uint4*)(esrc + baseA);
    uint4 qA0 = ((const uint4*)(eat + baseA))[0];
    uint4 qA1 = ((const uint4*)(eat + baseA))[1];
    uint4 qA2 = ((const uint4*)(eat + baseA))[2];
    uint4 qA3 = ((const uint4*)(eat + baseA))[3];
    u32 sA[8];
    sA[0] = spA.x & 0xffffu; sA[1] = spA.x >> 16;
    sA[2] = spA.y & 0xffffu; sA[3] = spA.y >> 16;
    sA[4] = spA.z & 0xffffu; sA[5] = spA.z >> 16;
    sA[6] = spA.w & 0xffffu; sA[7] = spA.w >> 16;
    uint2 aA[8];
    aA[0] = make_uint2(qA0.x, qA0.y); aA[1] = make_uint2(qA0.z, qA0.w);
    aA[2] = make_uint2(qA1.x, qA1.y); aA[3] = make_uint2(qA1.z, qA1.w);
    aA[4] = make_uint2(qA2.x, qA2.y); aA[5] = make_uint2(qA2.z, qA2.w);
    aA[6] = make_uint2(qA3.x, qA3.y); aA[7] = make_uint2(qA3.z, qA3.w);
    uint2 hA[8];
    u32 tA[8];
#pragma unroll
    for (int k = 0; k < 8; k++) {
      size_t s16 = (size_t)sA[k] * 16;
      hA[k] = hrow[s16];
      tA[k] = trow[s16];
    }
#pragma unroll
    for (int k = 0; k < 8; k++) {
      float A0 = bflo(hA[k].x), A1 = bfhi(hA[k].x);
      float A2 = bflo(hA[k].y), A3 = bfhi(hA[k].y);
      float A4 = bflo(tA[k]);
      float f0 = bflo(aA[k].x), f1 = bfhi(aA[k].x);
      float f2 = bflo(aA[k].y), f3 = bfhi(aA[k].y);
      R[0][0] += f0 * A0; R[0][1] += f0 * A1; R[0][2] += f0 * A2;
      R[0][3] += f0 * A3; R[0][4] += f0 * A4;
      R[1][0] += f1 * A0; R[1][1] += f1 * A1; R[1][2] += f1 * A2;
      R[1][3] += f1 * A3; R[1][4] += f1 * A4;
      R[2][0] += f2 * A0; R[2][1] += f2 * A1; R[2][2] += f2 * A2;
      R[2][3] += f2 * A3; R[2][4] += f2 * A4;
      R[3][0] += f3 * A0; R[3][1] += f3 * A1; R[3][2] += f3 * A2;
      R[3][3] += f3 * A3; R[3][4] += f3 * A4;
    }
  }

  // transpose into component-indexed LDS (quarter-private slice, wave-sync)
#pragma unroll
  for (int j = 0; j < 4; j++) {
#pragma unroll
    for (int k = 0; k < 4; k++) Rlds[q][j][4 * c + k] = R[j][k];
    Rlds[q][j][64 + c] = R[j][4];
  }

  // norm constants: 1/sqrt2 * path fan-in norm * 1/sqrt(DEG)
  const float C1 = 0.03125f;      // 1/(sqrt2*sqrt32*4)
  const float C2 = 0.025515518f;  // 1/(sqrt2*sqrt48*4)
  const float C3 = 0.03125f;      // 1/(sqrt2*sqrt32*4)
  const float C4 = 0.044194174f;  // 1/(sqrt2*sqrt16*4)

  u16* opm = omain + (size_t)n * 64;

  // scalar outputs c and c+16, fused over a
  float s0 = 0.f, s1 = 0.f;
#pragma unroll
  for (int a = 0; a < 32; a++) {
    float rs = Rlds[q][0][a];
    s0 += rs * w1[a * 32 + c];
    s1 += rs * w1[a * 32 + c + 16];
  }
  float t0 = 0.f, t1 = 0.f;
#pragma unroll
  for (int a = 0; a < 16; a++) {
    float T = Rlds[q][1][32 + 3 * a] + Rlds[q][2][33 + 3 * a] +
              Rlds[q][3][34 + 3 * a];
    t0 += T * w2[a * 32 + c];
    t1 += T * w2[a * 32 + c + 16];
  }

  float y[8];
  if (LAST) {
#pragma unroll
    for (int j = 0; j < 8; j++) y[j] = 0.f;
    float vs0 = C1 * s0 + C2 * t0;  // comp c
    float vs1 = C1 * s1 + C2 * t1;  // comp c+16
    vs0 = vs0 > 0.f ? vs0 : 0.f;
    vs1 = vs1 > 0.f ? vs1 : 0.f;
#pragma unroll
    for (int j = 0; j < 8; j++)
      y[j] += vs0 * Wout[c * 8 + j] + vs1 * Wout[(c + 16) * 8 + j];
  } else {
    opm[c] = f2bf(C1 * s0 + C2 * t0);
    opm[c + 16] = f2bf(C1 * s1 + C2 * t1);
  }

  // vector outputs: logical comps c2 = 32 + 16*i + c.
#pragma unroll
  for (int v2 = 0; v2 < 3; v2++) {
    int c2 = 32 + 16 * v2 + c;
    int cv = (c2 - 32) / 3, k = (c2 - 32) % 3;
    float a3 = 0.f, a4 = 0.f;
#pragma unroll
    for (int a = 0; a < 32; a++) a3 += Rlds[q][k + 1][a] * w3[a * 16 + cv];
#pragma unroll
    for (int a = 0; a < 16; a++)
      a4 += Rlds[q][0][32 + 3 * a + k] * w4[a * 16 + cv];
    float val = C3 * a3 + C4 * a4;
    if (LAST) {
      val = val > 0.f ? val : 0.f;
#pragma unroll
      for (int j = 0; j < 8; j++) y[j] += val * Wout[c2 * 8 + j];
    } else {
      u16 v = f2bf(val);
      if (v2 < 2) opm[32 + 16 * v2 + c] = v;
      else otail[(size_t)n * 16 + c] = v;
    }
  }

  if (LAST) {
    // quarter-wave (16-lane) reduction; xor masks 1,2,4,8 stay in-quarter
#pragma unroll
    for (int m = 1; m <= 8; m <<= 1) {
#pragma unroll
      for (int j = 0; j < 8; j++) y[j] += __shfl_xor(y[j], m, 64);
    }
    float w = y[0];
#pragma unroll
    for (int j = 1; j < 8; j++)
      if (c == j) w = y[j];
    if (c < 8) outp[(size_t)n * 8 + c] = w + bout[c];
  }
}

extern "C" void kernel_launch(void* const* d_in, const int* in_sizes, int n_in,
                              void* d_out, int out_size, void* d_ws,
                              size_t ws_size, hipStream_t stream) {
  const float* x = (const float*)d_in[0];
  const int* ei = (const int*)d_in[1];
  const float* eattr = (const float*)d_in[2];
  const float* W_in = (const float*)d_in[3];
  const float* b_in = (const float*)d_in[4];
  const float* tp_w1 = (const float*)d_in[5];
  const float* tp_w2 = (const float*)d_in[6];
  const float* tp_w3 = (const float*)d_in[7];
  const float* tp_w4 = (const float*)d_in[8];
  const float* W_out = (const float*)d_in[9];
  const float* b_out = (const float*)d_in[10];
  float* out = (float*)d_out;

  char* ws = (char*)d_ws;
  size_t off = 0;
  auto alloc = [&](size_t bytes) {
    void* p = ws + off;
    off += (bytes + 255) & ~size_t(255);
    return p;
  };
  const size_t NEP = (size_t)NE + 8 * (size_t)NN;
  u16* hm_a = (u16*)alloc((size_t)NN * 64 * 2);
  u16* ht_a = (u16*)alloc((size_t)NN * 16 * 2);
  u16* hm_b = (u16*)alloc((size_t)NN * 64 * 2);
  u16* ht_b = (u16*)alloc((size_t)NN * 16 * 2);
  int* counts = (int*)alloc((size_t)NN * 4);
  int* offsets = (int*)alloc((size_t)NN * 4);
  int* blocksum = (int*)alloc(64 * 4);
  int* rank = (int*)alloc((size_t)NE * 4);
  int* dcnt = (int*)alloc(16 * 4);
  int* brank = (int*)alloc((size_t)NN * 4);
  int* bidx = (int*)alloc((size_t)NN * 4);
  int* nperm = (int*)alloc((size_t)NN * 4);
  u16* esrc = (u16*)alloc(NEP * 2);
  uint2* eat = (uint2*)alloc(NEP * 8);

  const int* src = ei;
  const int* dst = ei + NE;

  hipMemsetAsync(counts, 0, (size_t)NN * 4, stream);
  k_in<<<(NN * 10 + 255) / 256, 256, 0, stream>>>(x, W_in, b_in, hm_a, ht_a);
  k_hist<<<NE / 2048, 256, 0, stream>>>(dst, counts, rank, dcnt);
  k_nb_scan<<<64 + NN / 256, 256, 0, stream>>>(counts, offsets, blocksum, dcnt,
                                               brank, bidx);
  k_scan2<<<2, 64, 0, stream>>>(blocksum, dcnt);
  k_node_fin<<<NN / 256, 256, 0, stream>>>(offsets, blocksum, counts, esrc,
                                           eat, dcnt, brank, bidx, nperm);
  k_fill<<<NE / 2048, 256, 0, stream>>>(src, dst, (const float4*)eattr,
                                        offsets, rank, esrc, eat);

  u16* hmi = hm_a;
  u16* hti = ht_a;
  u16* hmo = hm_b;
  u16* hto = ht_b;
  for (int l = 0; l < 2; l++) {
    k_msg<0><<<NN / 8, 128, 0, stream>>>(hmi, hti, hmo, hto, tp_w1 + l * 1024,
                                         tp_w2 + l * 512, tp_w3 + l * 512,
                                         tp_w4 + l * 256, offsets, counts,
                                         nperm, esrc, eat, W_out, b_out, out);
    u16* t;
    t = hmi; hmi = hmo; hmo = t;
    t = hti; hti = hto; hto = t;
  }
  k_msg<1><<<NN / 8, 128, 0, stream>>>(hmi, hti, hmo, hto, tp_w1 + 2048,
                                       tp_w2 + 1024, tp_w3 + 1024, tp_w4 + 512,
                                       offsets, counts, nperm, esrc, eat,
                                       W_out, b_out, out);
}